// Round 3
// baseline (101.036 us; speedup 1.0000x reference)
//
#include <hip/hip_runtime.h>
#include <math.h>

// Problem constants (B,S,H) = (4,512,128), ALIGN_STRENGTH = 1.0
namespace {
constexpr int Bn = 4;
constexpr int Sn = 512;
constexpr int Hn = 128;
constexpr int ROWS = 8;                      // output rows per block
constexpr int NBLK = Bn * (Sn / ROWS);       // 256 blocks -> 1 per CU
constexpr int NGRP = 8;                      // split-K groups
constexpr int NTHR = NGRP * 128;             // 1024 threads
constexpr int HCHUNK = Hn / NGRP;            // 16 h-values per group
constexpr int NACC = 2 * (ROWS + 1) + ROWS;  // 26 accumulators per (group,k)

__device__ inline float wave_sum(float v) {
    v += __shfl_xor(v, 32);
    v += __shfl_xor(v, 16);
    v += __shfl_xor(v, 8);
    v += __shfl_xor(v, 4);
    v += __shfl_xor(v, 2);
    v += __shfl_xor(v, 1);
    return v;
}
} // namespace

__global__ __launch_bounds__(NTHR) void tsa_kernel(
    const float* __restrict__ x,   const float* __restrict__ ref,
    const float* __restrict__ Wa,  const float* __restrict__ Wb,
    const float* __restrict__ b1,  const float* __restrict__ W2,
    const float* __restrict__ b2,  const float* __restrict__ Wp1,
    const float* __restrict__ bp1, const float* __restrict__ Wp2,
    const float* __restrict__ bp2, float* __restrict__ out)
{
    const int tid = threadIdx.x;
    const int k   = tid & 127;               // feature column 0..127
    const int grp = tid >> 7;                // split-K group 0..7
    const int b   = blockIdx.x >> 6;
    const int t0  = (blockIdx.x & 63) * ROWS;

    const float* xbase = x   + (size_t)b * Sn * Hn;
    const float* rbase = ref + (size_t)b * Sn * Hn;

    // Row i in [0..ROWS] maps to global row g = t0-1+i (clamped at 0; the
    // clamped row's A values only feed the t==0 copy path, which ignores them).
    const int g0 = (t0 == 0) ? 0 : (t0 - 1);

    // Partial accumulators over this group's h-chunk [grp*16, grp*16+16).
    float aa[ROWS + 1], cc[ROWS + 1], hp[ROWS];
#pragma unroll
    for (int i = 0; i <= ROWS; ++i) { aa[i] = 0.f; cc[i] = 0.f; }
#pragma unroll
    for (int j = 0; j < ROWS; ++j) hp[j] = 0.f;

    const int hbase = grp * HCHUNK;
#pragma unroll
    for (int h2 = 0; h2 < HCHUNK; h2 += 4) {
        const int h = hbase + h2;
        float wa[4], wb[4], wp[4];
#pragma unroll
        for (int u = 0; u < 4; ++u) {
            wa[u] = Wa[(h + u) * Hn + k];
            wb[u] = Wb[(h + u) * Hn + k];
            wp[u] = Wp1[(h + u) * Hn + k];
        }
#pragma unroll
        for (int i = 0; i <= ROWS; ++i) {
            const int g = (i == 0) ? g0 : (t0 - 1 + i);
            const float4 xv = *(const float4*)(xbase + (size_t)g * Hn + h);
            const float4 rv = *(const float4*)(rbase + (size_t)g * Hn + h);
            aa[i] += xv.x * wa[0]; aa[i] += xv.y * wa[1];
            aa[i] += xv.z * wa[2]; aa[i] += xv.w * wa[3];
            cc[i] += rv.x * wb[0]; cc[i] += rv.y * wb[1];
            cc[i] += rv.z * wb[2]; cc[i] += rv.w * wb[3];
            if (i >= 1) {
                hp[i-1] += xv.x * wp[0]; hp[i-1] += xv.y * wp[1];
                hp[i-1] += xv.z * wp[2]; hp[i-1] += xv.w * wp[3];
            }
        }
    }

    // LDS: partials [acc_idx][group][k]; after reduction the g=0 slot holds
    // the full sum.  26*1024 floats = 106 KB (1 block/CU, so no occupancy hit).
    __shared__ float pacc[NACC * NTHR];
    __shared__ float alphaA[ROWS];
    __shared__ int   opA[ROWS];

#pragma unroll
    for (int i = 0; i <= ROWS; ++i) {
        pacc[i * NTHR + grp * 128 + k]              = aa[i];
        pacc[(ROWS + 1 + i) * NTHR + grp * 128 + k] = cc[i];
    }
#pragma unroll
    for (int j = 0; j < ROWS; ++j)
        pacc[(2 * (ROWS + 1) + j) * NTHR + grp * 128 + k] = hp[j];
    __syncthreads();

    // Cross-group reduce: each (acc,k) summed by exactly one thread into g=0.
    for (int idx = tid; idx < NACC * 128; idx += NTHR) {
        const int i = idx >> 7, kk = idx & 127;
        float s = 0.f;
#pragma unroll
        for (int g = 0; g < NGRP; ++g) s += pacc[i * NTHR + g * 128 + kk];
        pacc[i * NTHR + kk] = s;
    }
    __syncthreads();

    // Phase 2: wave w (w<8) finalizes output row j = w; waves 8..15 idle here.
    // Lane l covers k = l and k = l+64.
    if (tid < ROWS * 64) {
        const int j  = tid >> 6;   // 0..7
        const int ln = tid & 63;
        float vm = 0.f, vi = 0.f, vd = 0.f, l0 = 0.f, l1 = 0.f, l2 = 0.f;
#pragma unroll
        for (int half = 0; half < 2; ++half) {
            const int kk = ln + 64 * half;
            const float at   = pacc[(j + 1) * NTHR + kk];
            const float atm1 = pacc[j * NTHR + kk];
            const float ct   = pacc[(ROWS + 1 + j + 1) * NTHR + kk];
            const float ctm1 = pacc[(ROWS + 1 + j) * NTHR + kk];
            const float hvp  = pacc[(2 * (ROWS + 1) + j) * NTHR + kk];
            const float b1k = b1[kk], w2k = W2[kk], bp1k = bp1[kk];
            vm += fmaxf(at   + ct   + b1k, 0.f) * w2k;   // A[t,t]
            vi += fmaxf(atm1 + ct   + b1k, 0.f) * w2k;   // A[t-1,t]
            vd += fmaxf(at   + ctm1 + b1k, 0.f) * w2k;   // A[t,t-1]
            const float hv = fmaxf(hvp + bp1k, 0.f);
            l0 += hv * Wp2[kk * 3 + 0];
            l1 += hv * Wp2[kk * 3 + 1];
            l2 += hv * Wp2[kk * 3 + 2];
        }
        vm = wave_sum(vm); vi = wave_sum(vi); vd = wave_sum(vd);
        l0 = wave_sum(l0); l1 = wave_sum(l1); l2 = wave_sum(l2);
        if (ln == 0) {
            const float b2v = b2[0];
            const float Am = 1.f / (1.f + expf(-(vm + b2v)));
            const float Ai = 1.f / (1.f + expf(-(vi + b2v)));
            const float Ad = 1.f / (1.f + expf(-(vd + b2v)));
            float q0 = l0 + bp2[0], q1 = l1 + bp2[1], q2 = l2 + bp2[2];
            const float mx  = fmaxf(q0, fmaxf(q1, q2));
            const float lse = mx + logf(expf(q0 - mx) + expf(q1 - mx) + expf(q2 - mx));
            const float s0 = Am * (q0 - lse);   // match
            const float s1 = Ai * (q1 - lse);   // insert
            const float s2 = Ad * (q2 - lse);   // delete
            // jnp.argmax: first occurrence of the max
            int op = 0; float best = s0;
            if (s1 > best) { op = 1; best = s1; }
            if (s2 > best) { op = 2; }
            opA[j]    = op;
            alphaA[j] = Am;   // ALIGN_STRENGTH == 1.0
        }
    }
    __syncthreads();

    // Output assembly: 8 rows x 128 cols = 1024 elements, 1 per thread.
    {
        const int e  = tid;
        const int j  = e >> 7;
        const int kk = e & 127;
        const int t  = t0 + j;
        float o;
        if (t == 0) {
            o = xbase[kk];
        } else {
            const int   op = opA[j];
            const float al = alphaA[j];
            const float xt   = xbase[(size_t)t * Hn + kk];
            const float rt   = rbase[(size_t)t * Hn + kk];
            const float xtm1 = xbase[(size_t)(t - 1) * Hn + kk];
            if (op == 0)      o = (1.f - al) * xt + al * rt;
            else if (op == 1) o = rt;
            else              o = xtm1;
        }
        out[((size_t)b * Sn + t) * Hn + kk] = o;
    }
}

extern "C" void kernel_launch(void* const* d_in, const int* in_sizes, int n_in,
                              void* d_out, int out_size, void* d_ws, size_t ws_size,
                              hipStream_t stream) {
    const float* x    = (const float*)d_in[0];
    const float* ref  = (const float*)d_in[1];
    const float* Wa   = (const float*)d_in[2];
    const float* Wb   = (const float*)d_in[3];
    const float* b1   = (const float*)d_in[4];
    const float* W2   = (const float*)d_in[5];
    const float* b2   = (const float*)d_in[6];
    const float* Wp1  = (const float*)d_in[7];
    const float* bp1  = (const float*)d_in[8];
    const float* Wp2  = (const float*)d_in[9];
    const float* bp2  = (const float*)d_in[10];
    float* out = (float*)d_out;

    tsa_kernel<<<NBLK, NTHR, 0, stream>>>(x, ref, Wa, Wb, b1, W2, b2,
                                          Wp1, bp1, Wp2, bp2, out);
}

// Round 4
// 82.507 us; speedup vs baseline: 1.2246x; 1.2246x over previous
//
#include <hip/hip_runtime.h>
#include <math.h>

// Problem constants (B,S,H) = (4,512,128), ALIGN_STRENGTH = 1.0
namespace {
constexpr int Bn = 4;
constexpr int Sn = 512;
constexpr int Hn = 128;
constexpr int ROWS = 8;                      // output rows per block
constexpr int NBLK = Bn * (Sn / ROWS);       // 256 blocks -> 1 per CU
constexpr int NGRP = 4;                      // split-K groups (R2 shape: best)
constexpr int NTHR = NGRP * 128;             // 512 threads, VGPR cap 256
constexpr int HCHUNK = Hn / NGRP;            // 32 h-values per group
constexpr int NACC = 2 * (ROWS + 1) + ROWS;  // 26 accumulators per (group,k)

__device__ inline float wave_sum(float v) {
    v += __shfl_xor(v, 32);
    v += __shfl_xor(v, 16);
    v += __shfl_xor(v, 8);
    v += __shfl_xor(v, 4);
    v += __shfl_xor(v, 2);
    v += __shfl_xor(v, 1);
    return v;
}
} // namespace

__global__ __launch_bounds__(NTHR) void tsa_kernel(
    const float* __restrict__ x,   const float* __restrict__ ref,
    const float* __restrict__ Wa,  const float* __restrict__ Wb,
    const float* __restrict__ b1,  const float* __restrict__ W2,
    const float* __restrict__ b2,  const float* __restrict__ Wp1,
    const float* __restrict__ bp1, const float* __restrict__ Wp2,
    const float* __restrict__ bp2, float* __restrict__ out)
{
    const int tid = threadIdx.x;
    const int k   = tid & 127;               // feature column 0..127
    const int grp = tid >> 7;                // split-K group 0..3
    const int b   = blockIdx.x >> 6;
    const int t0  = (blockIdx.x & 63) * ROWS;

    const float* xbase = x   + (size_t)b * Sn * Hn;
    const float* rbase = ref + (size_t)b * Sn * Hn;

    // Row i in [0..ROWS] maps to global row g = t0-1+i (clamped at 0; the
    // clamped row's A values only feed the t==0 copy path, which ignores them).
    const int g0 = (t0 == 0) ? 0 : (t0 - 1);

    // LDS: staged x/ref rows (9 KB), split-K partials (53 KB), row results.
    __shared__ float xs[(ROWS + 1) * Hn];
    __shared__ float rs[(ROWS + 1) * Hn];
    __shared__ float pacc[NACC * NTHR];
    __shared__ float alphaA[ROWS];
    __shared__ int   opA[ROWS];

    // Stage the 9 x-rows and 9 ref-rows once, coalesced float4.
    // (ROWS+1)*Hn/4 = 288 float4 per array; threads 0..287 take one each.
    for (int idx = tid; idx < (ROWS + 1) * (Hn / 4); idx += NTHR) {
        const int row = idx >> 5;            // Hn/4 = 32 float4 per row
        const int c4  = idx & 31;
        const int g   = (row == 0) ? g0 : (t0 - 1 + row);
        ((float4*)xs)[row * 32 + c4] = *(const float4*)(xbase + (size_t)g * Hn + c4 * 4);
        ((float4*)rs)[row * 32 + c4] = *(const float4*)(rbase + (size_t)g * Hn + c4 * 4);
    }
    __syncthreads();

    // Partial accumulators over this group's h-chunk [grp*32, grp*32+32).
    float aa[ROWS + 1], cc[ROWS + 1], hp[ROWS];
#pragma unroll
    for (int i = 0; i <= ROWS; ++i) { aa[i] = 0.f; cc[i] = 0.f; }
#pragma unroll
    for (int j = 0; j < ROWS; ++j) hp[j] = 0.f;

    const int hbase = grp * HCHUNK;
#pragma unroll
    for (int h2 = 0; h2 < HCHUNK; h2 += 4) {
        const int h = hbase + h2;
        // Only global traffic in the hot loop: 12 coalesced weight dwords.
        float wa[4], wb[4], wp[4];
#pragma unroll
        for (int u = 0; u < 4; ++u) {
            wa[u] = Wa[(h + u) * Hn + k];
            wb[u] = Wb[(h + u) * Hn + k];
            wp[u] = Wp1[(h + u) * Hn + k];
        }
#pragma unroll
        for (int i = 0; i <= ROWS; ++i) {
            // Wave-uniform LDS broadcast reads (no bank conflicts).
            const float4 xv = *(const float4*)(xs + i * Hn + h);
            const float4 rv = *(const float4*)(rs + i * Hn + h);
            aa[i] += xv.x * wa[0]; aa[i] += xv.y * wa[1];
            aa[i] += xv.z * wa[2]; aa[i] += xv.w * wa[3];
            cc[i] += rv.x * wb[0]; cc[i] += rv.y * wb[1];
            cc[i] += rv.z * wb[2]; cc[i] += rv.w * wb[3];
            if (i >= 1) {
                hp[i-1] += xv.x * wp[0]; hp[i-1] += xv.y * wp[1];
                hp[i-1] += xv.z * wp[2]; hp[i-1] += xv.w * wp[3];
            }
        }
    }

#pragma unroll
    for (int i = 0; i <= ROWS; ++i) {
        pacc[i * NTHR + grp * 128 + k]              = aa[i];
        pacc[(ROWS + 1 + i) * NTHR + grp * 128 + k] = cc[i];
    }
#pragma unroll
    for (int j = 0; j < ROWS; ++j)
        pacc[(2 * (ROWS + 1) + j) * NTHR + grp * 128 + k] = hp[j];
    __syncthreads();

    // Cross-group reduce: each (acc,k) summed by exactly one thread into g=0.
    for (int idx = tid; idx < NACC * 128; idx += NTHR) {
        const int i = idx >> 7, kk = idx & 127;
        float s = 0.f;
#pragma unroll
        for (int g = 0; g < NGRP; ++g) s += pacc[i * NTHR + g * 128 + kk];
        pacc[i * NTHR + kk] = s;
    }
    __syncthreads();

    // Phase 2: wave w finalizes output row j = w (8 waves, 8 rows).
    // Lane l covers k = l and k = l+64.
    {
        const int j  = tid >> 6;   // 0..7
        const int ln = tid & 63;
        float vm = 0.f, vi = 0.f, vd = 0.f, l0 = 0.f, l1 = 0.f, l2 = 0.f;
#pragma unroll
        for (int half = 0; half < 2; ++half) {
            const int kk = ln + 64 * half;
            const float at   = pacc[(j + 1) * NTHR + kk];
            const float atm1 = pacc[j * NTHR + kk];
            const float ct   = pacc[(ROWS + 1 + j + 1) * NTHR + kk];
            const float ctm1 = pacc[(ROWS + 1 + j) * NTHR + kk];
            const float hvp  = pacc[(2 * (ROWS + 1) + j) * NTHR + kk];
            const float b1k = b1[kk], w2k = W2[kk], bp1k = bp1[kk];
            vm += fmaxf(at   + ct   + b1k, 0.f) * w2k;   // A[t,t]
            vi += fmaxf(atm1 + ct   + b1k, 0.f) * w2k;   // A[t-1,t]
            vd += fmaxf(at   + ctm1 + b1k, 0.f) * w2k;   // A[t,t-1]
            const float hv = fmaxf(hvp + bp1k, 0.f);
            l0 += hv * Wp2[kk * 3 + 0];
            l1 += hv * Wp2[kk * 3 + 1];
            l2 += hv * Wp2[kk * 3 + 2];
        }
        vm = wave_sum(vm); vi = wave_sum(vi); vd = wave_sum(vd);
        l0 = wave_sum(l0); l1 = wave_sum(l1); l2 = wave_sum(l2);
        if (ln == 0) {
            const float b2v = b2[0];
            const float Am = 1.f / (1.f + expf(-(vm + b2v)));
            const float Ai = 1.f / (1.f + expf(-(vi + b2v)));
            const float Ad = 1.f / (1.f + expf(-(vd + b2v)));
            float q0 = l0 + bp2[0], q1 = l1 + bp2[1], q2 = l2 + bp2[2];
            const float mx  = fmaxf(q0, fmaxf(q1, q2));
            const float lse = mx + logf(expf(q0 - mx) + expf(q1 - mx) + expf(q2 - mx));
            const float s0 = Am * (q0 - lse);   // match
            const float s1 = Ai * (q1 - lse);   // insert
            const float s2 = Ad * (q2 - lse);   // delete
            // jnp.argmax: first occurrence of the max
            int op = 0; float best = s0;
            if (s1 > best) { op = 1; best = s1; }
            if (s2 > best) { op = 2; }
            opA[j]    = op;
            alphaA[j] = Am;   // ALIGN_STRENGTH == 1.0
        }
    }
    __syncthreads();

    // Output assembly from the staged LDS rows: xs[(j+1)] = x[t], xs[j] =
    // x[t-1], rs[(j+1)] = ref[t].  1024 elements, 2 per thread.
    for (int e = tid; e < ROWS * 128; e += NTHR) {
        const int j  = e >> 7;
        const int kk = e & 127;
        const int t  = t0 + j;
        float o;
        if (t == 0) {
            o = xs[1 * Hn + kk];             // row i=1 holds global row 0
        } else {
            const int   op = opA[j];
            const float al = alphaA[j];
            const float xt   = xs[(j + 1) * Hn + kk];
            const float rt   = rs[(j + 1) * Hn + kk];
            const float xtm1 = xs[j * Hn + kk];
            if (op == 0)      o = (1.f - al) * xt + al * rt;
            else if (op == 1) o = rt;
            else              o = xtm1;
        }
        out[((size_t)b * Sn + t) * Hn + kk] = o;
    }
}

extern "C" void kernel_launch(void* const* d_in, const int* in_sizes, int n_in,
                              void* d_out, int out_size, void* d_ws, size_t ws_size,
                              hipStream_t stream) {
    const float* x    = (const float*)d_in[0];
    const float* ref  = (const float*)d_in[1];
    const float* Wa   = (const float*)d_in[2];
    const float* Wb   = (const float*)d_in[3];
    const float* b1   = (const float*)d_in[4];
    const float* W2   = (const float*)d_in[5];
    const float* b2   = (const float*)d_in[6];
    const float* Wp1  = (const float*)d_in[7];
    const float* bp1  = (const float*)d_in[8];
    const float* Wp2  = (const float*)d_in[9];
    const float* bp2  = (const float*)d_in[10];
    float* out = (float*)d_out;

    tsa_kernel<<<NBLK, NTHR, 0, stream>>>(x, ref, Wa, Wb, b1, W2, b2,
                                          Wp1, bp1, Wp2, bp2, out);
}

// Round 5
// 81.926 us; speedup vs baseline: 1.2333x; 1.0071x over previous
//
#include <hip/hip_runtime.h>
#include <math.h>

// Problem constants (B,S,H) = (4,512,128), ALIGN_STRENGTH = 1.0
namespace {
constexpr int Bn = 4;
constexpr int Sn = 512;
constexpr int Hn = 128;
constexpr int ROWS = 8;                      // output rows per block
constexpr int NBLK = Bn * (Sn / ROWS);       // 256 blocks -> 1 per CU
constexpr int NGRP = 8;                      // split-K groups == waves
constexpr int NTHR = NGRP * 64;              // 512 threads, 8 waves
constexpr int HCHUNK = Hn / NGRP;            // 16 h-values per wave-group
constexpr int NACC = 2 * (ROWS + 1) + ROWS;  // 26 accumulator rows

__device__ inline float wave_sum(float v) {
    v += __shfl_xor(v, 32);
    v += __shfl_xor(v, 16);
    v += __shfl_xor(v, 8);
    v += __shfl_xor(v, 4);
    v += __shfl_xor(v, 2);
    v += __shfl_xor(v, 1);
    return v;
}
} // namespace

__global__ __launch_bounds__(NTHR) void tsa_kernel(
    const float* __restrict__ x,   const float* __restrict__ ref,
    const float* __restrict__ Wa,  const float* __restrict__ Wb,
    const float* __restrict__ b1,  const float* __restrict__ W2,
    const float* __restrict__ b2,  const float* __restrict__ Wp1,
    const float* __restrict__ bp1, const float* __restrict__ Wp2,
    const float* __restrict__ bp2, float* __restrict__ out)
{
    const int tid  = threadIdx.x;
    const int lane = tid & 63;
    const int grp  = tid >> 6;               // wave index == split-K group 0..7
    const int b    = blockIdx.x >> 6;
    const int t0   = (blockIdx.x & 63) * ROWS;
    const int k0   = lane;                   // this thread's two feature cols
    const int k1   = lane + 64;

    const float* xbase = x   + (size_t)b * Sn * Hn;
    const float* rbase = ref + (size_t)b * Sn * Hn;

    // Row i in [0..ROWS] maps to global row g = t0-1+i (clamped at 0; the
    // clamped row's A values only feed the t==0 copy path, which ignores them).
    const int g0 = (t0 == 0) ? 0 : (t0 - 1);

    // LDS: staged x/ref rows (9 KB), split-K partials [acc][group][k] (104 KB).
    __shared__ float xs[(ROWS + 1) * Hn];
    __shared__ float rs[(ROWS + 1) * Hn];
    __shared__ float pacc[NACC * NGRP * Hn];
    __shared__ float alphaA[ROWS];
    __shared__ int   opA[ROWS];

    // Stage the 9 x-rows and 9 ref-rows once, coalesced float4.
    for (int idx = tid; idx < (ROWS + 1) * (Hn / 4); idx += NTHR) {
        const int row = idx >> 5;            // Hn/4 = 32 float4 per row
        const int c4  = idx & 31;
        const int g   = (row == 0) ? g0 : (t0 - 1 + row);
        ((float4*)xs)[row * 32 + c4] = *(const float4*)(xbase + (size_t)g * Hn + c4 * 4);
        ((float4*)rs)[row * 32 + c4] = *(const float4*)(rbase + (size_t)g * Hn + c4 * 4);
    }
    __syncthreads();

    // Partial accumulators over this wave's h-chunk [grp*16, grp*16+16),
    // 2 feature columns per thread.
    float aa[ROWS + 1][2], cc[ROWS + 1][2], hp[ROWS][2];
#pragma unroll
    for (int i = 0; i <= ROWS; ++i) { aa[i][0]=0.f; aa[i][1]=0.f; cc[i][0]=0.f; cc[i][1]=0.f; }
#pragma unroll
    for (int j = 0; j < ROWS; ++j) { hp[j][0]=0.f; hp[j][1]=0.f; }

    const int hbase = grp * HCHUNK;
#pragma unroll
    for (int h2 = 0; h2 < HCHUNK; h2 += 4) {
        const int h = hbase + h2;
        // Only global traffic in the hot loop: 24 coalesced weight dwords.
        float wa[4][2], wb[4][2], wp[4][2];
#pragma unroll
        for (int u = 0; u < 4; ++u) {
            wa[u][0] = Wa[(h + u) * Hn + k0];  wa[u][1] = Wa[(h + u) * Hn + k1];
            wb[u][0] = Wb[(h + u) * Hn + k0];  wb[u][1] = Wb[(h + u) * Hn + k1];
            wp[u][0] = Wp1[(h + u) * Hn + k0]; wp[u][1] = Wp1[(h + u) * Hn + k1];
        }
#pragma unroll
        for (int i = 0; i <= ROWS; ++i) {
            // Wave-uniform LDS broadcast reads (no bank conflicts).
            const float4 xv = *(const float4*)(xs + i * Hn + h);
            const float4 rv = *(const float4*)(rs + i * Hn + h);
#pragma unroll
            for (int c = 0; c < 2; ++c) {
                aa[i][c] += xv.x * wa[0][c]; aa[i][c] += xv.y * wa[1][c];
                aa[i][c] += xv.z * wa[2][c]; aa[i][c] += xv.w * wa[3][c];
                cc[i][c] += rv.x * wb[0][c]; cc[i][c] += rv.y * wb[1][c];
                cc[i][c] += rv.z * wb[2][c]; cc[i][c] += rv.w * wb[3][c];
            }
            if (i >= 1) {
#pragma unroll
                for (int c = 0; c < 2; ++c) {
                    hp[i-1][c] += xv.x * wp[0][c]; hp[i-1][c] += xv.y * wp[1][c];
                    hp[i-1][c] += xv.z * wp[2][c]; hp[i-1][c] += xv.w * wp[3][c];
                }
            }
        }
    }

    // Store partials: pacc[(acc*NGRP + grp)*Hn + k]  (k-consecutive per lane:
    // conflict-free stores; k-contiguous per (acc,grp): float4-able reduce).
#pragma unroll
    for (int i = 0; i <= ROWS; ++i) {
        pacc[(i * NGRP + grp) * Hn + k0]              = aa[i][0];
        pacc[(i * NGRP + grp) * Hn + k1]              = aa[i][1];
        pacc[((ROWS + 1 + i) * NGRP + grp) * Hn + k0] = cc[i][0];
        pacc[((ROWS + 1 + i) * NGRP + grp) * Hn + k1] = cc[i][1];
    }
#pragma unroll
    for (int j = 0; j < ROWS; ++j) {
        pacc[((2 * (ROWS + 1) + j) * NGRP + grp) * Hn + k0] = hp[j][0];
        pacc[((2 * (ROWS + 1) + j) * NGRP + grp) * Hn + k1] = hp[j][1];
    }
    __syncthreads();

    // Cross-group reduce, float4-vectorized: 26*32 = 832 column-tasks.
    // Result for acc i lands at pacc[i*NGRP*Hn + k] (the g=0 slot).
    for (int idx = tid; idx < NACC * (Hn / 4); idx += NTHR) {
        const int i  = idx >> 5;
        const int c4 = idx & 31;
        float4 s = make_float4(0.f, 0.f, 0.f, 0.f);
#pragma unroll
        for (int g = 0; g < NGRP; ++g) {
            const float4 v = ((const float4*)pacc)[(i * NGRP + g) * (Hn / 4) + c4];
            s.x += v.x; s.y += v.y; s.z += v.z; s.w += v.w;
        }
        ((float4*)pacc)[(i * NGRP) * (Hn / 4) + c4] = s;
    }
    __syncthreads();

    // Phase 2: wave w finalizes output row j = w (8 waves, 8 rows).
    // Final acc i lives at pacc[i*1024 + kk].
    {
        const int j  = tid >> 6;   // 0..7
        const int ln = tid & 63;
        float vm = 0.f, vi = 0.f, vd = 0.f, l0 = 0.f, l1 = 0.f, l2 = 0.f;
#pragma unroll
        for (int half = 0; half < 2; ++half) {
            const int kk = ln + 64 * half;
            const float at   = pacc[(j + 1) * (NGRP * Hn) + kk];
            const float atm1 = pacc[j * (NGRP * Hn) + kk];
            const float ct   = pacc[(ROWS + 1 + j + 1) * (NGRP * Hn) + kk];
            const float ctm1 = pacc[(ROWS + 1 + j) * (NGRP * Hn) + kk];
            const float hvp  = pacc[(2 * (ROWS + 1) + j) * (NGRP * Hn) + kk];
            const float b1k = b1[kk], w2k = W2[kk], bp1k = bp1[kk];
            vm += fmaxf(at   + ct   + b1k, 0.f) * w2k;   // A[t,t]
            vi += fmaxf(atm1 + ct   + b1k, 0.f) * w2k;   // A[t-1,t]
            vd += fmaxf(at   + ctm1 + b1k, 0.f) * w2k;   // A[t,t-1]
            const float hv = fmaxf(hvp + bp1k, 0.f);
            l0 += hv * Wp2[kk * 3 + 0];
            l1 += hv * Wp2[kk * 3 + 1];
            l2 += hv * Wp2[kk * 3 + 2];
        }
        vm = wave_sum(vm); vi = wave_sum(vi); vd = wave_sum(vd);
        l0 = wave_sum(l0); l1 = wave_sum(l1); l2 = wave_sum(l2);
        if (ln == 0) {
            const float b2v = b2[0];
            const float Am = 1.f / (1.f + expf(-(vm + b2v)));
            const float Ai = 1.f / (1.f + expf(-(vi + b2v)));
            const float Ad = 1.f / (1.f + expf(-(vd + b2v)));
            float q0 = l0 + bp2[0], q1 = l1 + bp2[1], q2 = l2 + bp2[2];
            const float mx  = fmaxf(q0, fmaxf(q1, q2));
            const float lse = mx + logf(expf(q0 - mx) + expf(q1 - mx) + expf(q2 - mx));
            const float s0 = Am * (q0 - lse);   // match
            const float s1 = Ai * (q1 - lse);   // insert
            const float s2 = Ad * (q2 - lse);   // delete
            // jnp.argmax: first occurrence of the max
            int op = 0; float best = s0;
            if (s1 > best) { op = 1; best = s1; }
            if (s2 > best) { op = 2; }
            opA[j]    = op;
            alphaA[j] = Am;   // ALIGN_STRENGTH == 1.0
        }
    }
    __syncthreads();

    // Output assembly from the staged LDS rows: xs[(j+1)] = x[t], xs[j] =
    // x[t-1], rs[(j+1)] = ref[t].  1024 elements, 2 per thread.
    for (int e = tid; e < ROWS * 128; e += NTHR) {
        const int j  = e >> 7;
        const int kk = e & 127;
        const int t  = t0 + j;
        float o;
        if (t == 0) {
            o = xs[1 * Hn + kk];             // row i=1 holds global row 0
        } else {
            const int   op = opA[j];
            const float al = alphaA[j];
            const float xt   = xs[(j + 1) * Hn + kk];
            const float rt   = rs[(j + 1) * Hn + kk];
            const float xtm1 = xs[j * Hn + kk];
            if (op == 0)      o = (1.f - al) * xt + al * rt;
            else if (op == 1) o = rt;
            else              o = xtm1;
        }
        out[((size_t)b * Sn + t) * Hn + kk] = o;
    }
}

extern "C" void kernel_launch(void* const* d_in, const int* in_sizes, int n_in,
                              void* d_out, int out_size, void* d_ws, size_t ws_size,
                              hipStream_t stream) {
    const float* x    = (const float*)d_in[0];
    const float* ref  = (const float*)d_in[1];
    const float* Wa   = (const float*)d_in[2];
    const float* Wb   = (const float*)d_in[3];
    const float* b1   = (const float*)d_in[4];
    const float* W2   = (const float*)d_in[5];
    const float* b2   = (const float*)d_in[6];
    const float* Wp1  = (const float*)d_in[7];
    const float* bp1  = (const float*)d_in[8];
    const float* Wp2  = (const float*)d_in[9];
    const float* bp2  = (const float*)d_in[10];
    float* out = (float*)d_out;

    tsa_kernel<<<NBLK, NTHR, 0, stream>>>(x, ref, Wa, Wb, b1, W2, b2,
                                          Wp1, bp1, Wp2, bp2, out);
}